// Round 4
// baseline (9057.378 us; speedup 1.0000x reference)
//
#include <hip/hip_runtime.h>
#include <hip/hip_bf16.h>

// Model dims (fixed by the reference)
#define BATCH  4
#define SEQ    512
#define TOK    (BATCH*SEQ)     // 2048
#define HID    512
#define NHEAD  8
#define HEAD   64
#define FFDIM  2048
#define NLAYER 12
#define SPAN2  1024            // 2*SPAN
#define VOCAB  25
#define LNEPS  1e-7f
#define NEG_BIG -3.0e38f

__device__ __forceinline__ float b2f(unsigned short u) {
    return __uint_as_float(((unsigned int)u) << 16);
}
__device__ __forceinline__ unsigned short f2b(float f) {
    __hip_bfloat16 h = __float2bfloat16(f);
    return *(unsigned short*)&h;
}

// ---------------- block reductions (blockDim = 256, 1-D) ----------------
__device__ __forceinline__ float block_reduce_sum(float v, float* red) {
    int tid = threadIdx.x;
    red[tid] = v; __syncthreads();
    for (int s = 128; s > 0; s >>= 1) { if (tid < s) red[tid] += red[tid + s]; __syncthreads(); }
    float r = red[0]; __syncthreads();
    return r;
}

// ---------------- embedding gather + LN + mask ----------------
__global__ void embed_ln_kernel(const int* __restrict__ x, const int* __restrict__ am,
                                const float* __restrict__ word_emb,
                                const float* __restrict__ g, const float* __restrict__ bb,
                                float* __restrict__ h) {
    __shared__ float red[256];
    int t = blockIdx.x, tid = threadIdx.x;
    const float* we = word_emb + (size_t)x[t] * HID;
    float v1 = we[tid], v2 = we[tid + 256];
    float mean = block_reduce_sum(v1 + v2, red) * (1.0f / HID);
    float d1 = v1 - mean, d2 = v2 - mean;
    float var = block_reduce_sum(d1 * d1 + d2 * d2, red) * (1.0f / HID);
    float rstd = rsqrtf(var + LNEPS);
    float maskf = (float)am[t];
    size_t base = (size_t)t * HID;
    h[base + tid]       = (d1 * rstd * g[tid]       + bb[tid])       * maskf;
    h[base + tid + 256] = (d2 * rstd * g[tid + 256] + bb[tid + 256]) * maskf;
}

// ---------------- residual add + LN (writes h in place) ----------------
__global__ void add_ln_kernel(const float* __restrict__ tmp,
                              const float* __restrict__ g, const float* __restrict__ bb,
                              float* __restrict__ h) {
    __shared__ float red[256];
    int t = blockIdx.x, tid = threadIdx.x;
    size_t base = (size_t)t * HID;
    float v1 = tmp[base + tid] + h[base + tid];
    float v2 = tmp[base + tid + 256] + h[base + tid + 256];
    float mean = block_reduce_sum(v1 + v2, red) * (1.0f / HID);
    float d1 = v1 - mean, d2 = v2 - mean;
    float var = block_reduce_sum(d1 * d1 + d2 * d2, red) * (1.0f / HID);
    float rstd = rsqrtf(var + LNEPS);
    h[base + tid]       = d1 * rstd * g[tid]       + bb[tid];
    h[base + tid + 256] = d2 * rstd * g[tid + 256] + bb[tid + 256];
}

// ---------------- generic GEMM: C[M,N] = A[M,K] @ B[K,N](fp32) + bias(fp32) ----------------
// AMODE: 0 = fp32 A, 1 = bf16 A. OUT_BF16 selects C dtype. Optional exact gelu.
// block (16,16), 64x64 tile, 4x4 per thread, K-tiles of 16. M%64==0, N%64==0, K%16==0.
template<int AMODE, bool OUT_BF16, bool GELU>
__global__ __launch_bounds__(256) void gemm_t(
    const void* __restrict__ Ap, const float* __restrict__ B,
    const float* __restrict__ bias, void* __restrict__ Cp,
    int M, int N, int K) {
    __shared__ float As[16][65];
    __shared__ float Bs[16][65];
    int tid = threadIdx.y * 16 + threadIdx.x;
    int row0 = blockIdx.y * 64, col0 = blockIdx.x * 64;
    int am_ = tid >> 2, ak = (tid & 3) << 2;    // A: row, 4 consecutive k
    int bk = tid >> 4, bn = (tid & 15) << 2;    // B: k-row, 4 consecutive n
    float acc[4][4] = {};
    for (int k0 = 0; k0 < K; k0 += 16) {
        float4 av;
        size_t aidx = (size_t)(row0 + am_) * K + ak + k0;
        if (AMODE == 0) {
            av = *(const float4*)((const float*)Ap + aidx);
        } else {
            ushort4 u = *(const ushort4*)((const unsigned short*)Ap + aidx);
            av = make_float4(b2f(u.x), b2f(u.y), b2f(u.z), b2f(u.w));
        }
        As[ak + 0][am_] = av.x; As[ak + 1][am_] = av.y;
        As[ak + 2][am_] = av.z; As[ak + 3][am_] = av.w;
        float4 bv = *(const float4*)(B + (size_t)(k0 + bk) * N + col0 + bn);
        Bs[bk][bn + 0] = bv.x; Bs[bk][bn + 1] = bv.y;
        Bs[bk][bn + 2] = bv.z; Bs[bk][bn + 3] = bv.w;
        __syncthreads();
        #pragma unroll
        for (int kk = 0; kk < 16; kk++) {
            float a[4], b[4];
            #pragma unroll
            for (int i = 0; i < 4; i++) a[i] = As[kk][(threadIdx.y << 2) + i];
            #pragma unroll
            for (int j = 0; j < 4; j++) b[j] = Bs[kk][(threadIdx.x << 2) + j];
            #pragma unroll
            for (int i = 0; i < 4; i++)
                #pragma unroll
                for (int j = 0; j < 4; j++) acc[i][j] += a[i] * b[j];
        }
        __syncthreads();
    }
    #pragma unroll
    for (int i = 0; i < 4; i++) {
        int row = row0 + (threadIdx.y << 2) + i;
        #pragma unroll
        for (int j = 0; j < 4; j++) {
            int col = col0 + (threadIdx.x << 2) + j;
            float v = acc[i][j] + bias[col];
            if (GELU) v = 0.5f * v * (1.0f + erff(v * 0.70710678118654752f));
            if (OUT_BF16) ((unsigned short*)Cp)[(size_t)row * N + col] = f2b(v);
            else          ((float*)Cp)[(size_t)row * N + col] = v;
        }
    }
}

// ---------------- fused flash-style disentangled attention ----------------
// s[q,k] = (Q_q.K_k + Q_q.pk[q-k+512] + K_k.pq[q-k+512]) / sqrt(192), online softmax, @V.
// grid (qtile=16, bh=32), block (16,16). All tensor operands are ws bf16.
__global__ __launch_bounds__(256) void attn_kernel(
    const unsigned short* __restrict__ Q, const unsigned short* __restrict__ K,
    const unsigned short* __restrict__ V,
    const unsigned short* __restrict__ PK, const unsigned short* __restrict__ PQ,
    const int* __restrict__ am, unsigned short* __restrict__ ctx) {
    __shared__ float Qs[32][65], Ks[32][65], Vs[32][65];
    __shared__ float PKs[63][65], PQs[63][65];
    __shared__ float Ss[32][33];
    __shared__ float mrow[32], lrow[32], arow[32];
    __shared__ int mkk[32];
    int bh = blockIdx.y, b = bh >> 3, hh = bh & 7;
    int q0 = blockIdx.x * 32;
    int tid = threadIdx.y * 16 + threadIdx.x;
    const float inv_scale = 0.07216878364870323f; // 1/sqrt(192)

    {   // Q tile 32x64
        int r = tid >> 3, c = (tid & 7) * 8;
        const unsigned short* qp = Q + ((size_t)(b * SEQ + q0 + r) * HID) + hh * HEAD + c;
        ushort4 a = *(const ushort4*)qp, a2 = *(const ushort4*)(qp + 4);
        Qs[r][c] = b2f(a.x); Qs[r][c+1] = b2f(a.y); Qs[r][c+2] = b2f(a.z); Qs[r][c+3] = b2f(a.w);
        Qs[r][c+4] = b2f(a2.x); Qs[r][c+5] = b2f(a2.y); Qs[r][c+6] = b2f(a2.z); Qs[r][c+7] = b2f(a2.w);
    }
    if (tid < 32) { mrow[tid] = NEG_BIG; lrow[tid] = 0.0f; }
    float acc0[4] = {}, acc1[4] = {};
    int rowA = threadIdx.y * 2, dA = threadIdx.x * 4;

    for (int k0 = 0; k0 < SEQ; k0 += 32) {
        __syncthreads();
        {   // K, V tiles 32x64
            int r = tid >> 3, c = (tid & 7) * 8;
            const unsigned short* kp = K + ((size_t)(b * SEQ + k0 + r) * HID) + hh * HEAD + c;
            ushort4 a = *(const ushort4*)kp, a2 = *(const ushort4*)(kp + 4);
            Ks[r][c] = b2f(a.x); Ks[r][c+1] = b2f(a.y); Ks[r][c+2] = b2f(a.z); Ks[r][c+3] = b2f(a.w);
            Ks[r][c+4] = b2f(a2.x); Ks[r][c+5] = b2f(a2.y); Ks[r][c+6] = b2f(a2.z); Ks[r][c+7] = b2f(a2.w);
            const unsigned short* vp = V + ((size_t)(b * SEQ + k0 + r) * HID) + hh * HEAD + c;
            ushort4 e = *(const ushort4*)vp, e2 = *(const ushort4*)(vp + 4);
            Vs[r][c] = b2f(e.x); Vs[r][c+1] = b2f(e.y); Vs[r][c+2] = b2f(e.z); Vs[r][c+3] = b2f(e.w);
            Vs[r][c+4] = b2f(e2.x); Vs[r][c+5] = b2f(e2.y); Vs[r][c+6] = b2f(e2.z); Vs[r][c+7] = b2f(e2.w);
        }
        int d0 = q0 - k0 + 481;  // window base in [1,961]; +62 <= 1023, no clamp binds
        for (int idx = tid; idx < 63 * 8; idx += 256) {
            int r = idx >> 3, c = (idx & 7) * 8;
            const unsigned short* pkp = PK + (size_t)(d0 + r) * HID + hh * HEAD + c;
            ushort4 a = *(const ushort4*)pkp, a2 = *(const ushort4*)(pkp + 4);
            PKs[r][c] = b2f(a.x); PKs[r][c+1] = b2f(a.y); PKs[r][c+2] = b2f(a.z); PKs[r][c+3] = b2f(a.w);
            PKs[r][c+4] = b2f(a2.x); PKs[r][c+5] = b2f(a2.y); PKs[r][c+6] = b2f(a2.z); PKs[r][c+7] = b2f(a2.w);
            const unsigned short* pqp = PQ + (size_t)(d0 + r) * HID + hh * HEAD + c;
            ushort4 e = *(const ushort4*)pqp, e2 = *(const ushort4*)(pqp + 4);
            PQs[r][c] = b2f(e.x); PQs[r][c+1] = b2f(e.y); PQs[r][c+2] = b2f(e.z); PQs[r][c+3] = b2f(e.w);
            PQs[r][c+4] = b2f(e2.x); PQs[r][c+5] = b2f(e2.y); PQs[r][c+6] = b2f(e2.z); PQs[r][c+7] = b2f(e2.w);
        }
        if (tid < 32) mkk[tid] = am[b * SEQ + k0 + tid];
        __syncthreads();

        {   // scores 2x2 per thread
            int qq0 = threadIdx.y * 2, kk0 = threadIdx.x * 2;
            int dr = qq0 - kk0 + 31;   // in [1,61]
            float s00 = 0, s01 = 0, s10 = 0, s11 = 0;
            #pragma unroll 8
            for (int d = 0; d < 64; d++) {
                float q0v = Qs[qq0][d],     q1v = Qs[qq0 + 1][d];
                float k0v = Ks[kk0][d],     k1v = Ks[kk0 + 1][d];
                float pkm = PKs[dr - 1][d], pk0 = PKs[dr][d], pkp = PKs[dr + 1][d];
                float pqm = PQs[dr - 1][d], pq0 = PQs[dr][d], pqp = PQs[dr + 1][d];
                s00 += q0v * (k0v + pk0) + k0v * pq0;
                s01 += q0v * (k1v + pkm) + k1v * pqm;
                s10 += q1v * (k0v + pkp) + k0v * pqp;
                s11 += q1v * (k1v + pk0) + k1v * pq0;
            }
            Ss[qq0][kk0]         = s00 * inv_scale;
            Ss[qq0][kk0 + 1]     = s01 * inv_scale;
            Ss[qq0 + 1][kk0]     = s10 * inv_scale;
            Ss[qq0 + 1][kk0 + 1] = s11 * inv_scale;
        }
        __syncthreads();

        {   // online softmax: row r, 4 cols per thread, 8 threads/row
            int r = tid >> 3, cg = (tid & 7) * 4;
            float sv[4]; float tmax = NEG_BIG;
            #pragma unroll
            for (int j = 0; j < 4; j++) {
                sv[j] = mkk[cg + j] ? Ss[r][cg + j] : NEG_BIG;
                tmax = fmaxf(tmax, sv[j]);
            }
            tmax = fmaxf(tmax, __shfl_xor(tmax, 1));
            tmax = fmaxf(tmax, __shfl_xor(tmax, 2));
            tmax = fmaxf(tmax, __shfl_xor(tmax, 4));
            float mold = mrow[r];
            float mnew = fmaxf(mold, tmax);
            float psum = 0.0f;
            #pragma unroll
            for (int j = 0; j < 4; j++) {
                float p = (sv[j] > -1.5e38f) ? __expf(sv[j] - mnew) : 0.0f;
                Ss[r][cg + j] = p;
                psum += p;
            }
            psum += __shfl_xor(psum, 1);
            psum += __shfl_xor(psum, 2);
            psum += __shfl_xor(psum, 4);
            if ((tid & 7) == 0) {
                float alpha = __expf(mold - mnew);
                mrow[r] = mnew;
                lrow[r] = lrow[r] * alpha + psum;
                arow[r] = alpha;
            }
        }
        __syncthreads();

        {   // acc update: 2 rows x 4 d per thread
            float a0 = arow[rowA], a1 = arow[rowA + 1];
            #pragma unroll
            for (int j = 0; j < 4; j++) { acc0[j] *= a0; acc1[j] *= a1; }
            #pragma unroll 8
            for (int kk = 0; kk < 32; kk++) {
                float p0 = Ss[rowA][kk], p1 = Ss[rowA + 1][kk];
                #pragma unroll
                for (int j = 0; j < 4; j++) {
                    float vv = Vs[kk][dA + j];
                    acc0[j] += p0 * vv;
                    acc1[j] += p1 * vv;
                }
            }
        }
    }
    // epilogue
    float l0 = lrow[rowA], l1 = lrow[rowA + 1];
    float inv0 = l0 > 0.0f ? 1.0f / l0 : 0.0f;
    float inv1 = l1 > 0.0f ? 1.0f / l1 : 0.0f;
    inv0 *= (float)am[b * SEQ + q0 + rowA];
    inv1 *= (float)am[b * SEQ + q0 + rowA + 1];
    size_t base0 = ((size_t)(b * SEQ + q0 + rowA) * HID) + hh * HEAD + dA;
    size_t base1 = base0 + HID;
    #pragma unroll
    for (int j = 0; j < 4; j++) {
        ctx[base0 + j] = f2b(acc0[j] * inv0);
        ctx[base1 + j] = f2b(acc1[j] * inv1);
    }
}

// ---------------- output copy / classifier (fp32 out) ----------------
__global__ void copy_f_kernel(const float* __restrict__ in, float* __restrict__ out, int n) {
    int i = blockIdx.x * 256 + threadIdx.x;
    if (i < n) out[i] = in[i];
}
__global__ void cls_kernel(const float* __restrict__ h, const float* __restrict__ cls_w,
                           const float* __restrict__ cls_b, float* __restrict__ out) {
    int t = blockIdx.x, v = threadIdx.x;
    if (v < VOCAB) {
        const float* hr = h + (size_t)t * HID;
        const float* wr = cls_w + (size_t)v * HID;
        float acc = cls_b[v];
        for (int d = 0; d < HID; d++) acc += hr[d] * wr[d];
        out[t * VOCAB + v] = acc;
    }
}

extern "C" void kernel_launch(void* const* d_in, const int* in_sizes, int n_in,
                              void* d_out, int out_size, void* d_ws, size_t ws_size,
                              hipStream_t stream) {
    const int* x     = (const int*)d_in[0];
    const int* am    = (const int*)d_in[1];
    const float* word_emb = (const float*)d_in[2];
    const float* emb_g    = (const float*)d_in[3];
    const float* emb_b    = (const float*)d_in[4];
    const float* rel_emb  = (const float*)d_in[5];
    const float* Wq  = (const float*)d_in[6];  const float* bq  = (const float*)d_in[7];
    const float* Wk  = (const float*)d_in[8];  const float* bk  = (const float*)d_in[9];
    const float* Wv  = (const float*)d_in[10]; const float* bv  = (const float*)d_in[11];
    const float* Wpk = (const float*)d_in[12]; const float* bpk = (const float*)d_in[13];
    const float* Wpq = (const float*)d_in[14]; const float* bpq = (const float*)d_in[15];
    const float* Wo  = (const float*)d_in[16]; const float* bo  = (const float*)d_in[17];
    const float* ln1g = (const float*)d_in[18]; const float* ln1b = (const float*)d_in[19];
    const float* W1  = (const float*)d_in[20]; const float* b1  = (const float*)d_in[21];
    const float* W2  = (const float*)d_in[22]; const float* b2  = (const float*)d_in[23];
    const float* ln2g = (const float*)d_in[24]; const float* ln2b = (const float*)d_in[25];
    const float* cls_w = (const float*)d_in[26]; const float* cls_b = (const float*)d_in[27];

    // ---- workspace layout: 18 MB + 256 B (19 MB proven available in R3) ----
    const size_t NEEDED = 19u * 1024u * 1024u;
    if (ws_size < NEEDED) return;  // signal: zero-output signature => ws too small
    char* wsb = (char*)d_ws;
    float* h  = (float*)(wsb + 256);                           // 4 MB
    float* t1 = (float*)(wsb + 256 + (4u << 20));              // 4 MB
    unsigned short* qb  = (unsigned short*)(wsb + 256 + (8u << 20)); // 2 MB
    unsigned short* kb  = qb  + (1u << 20);                    // 2 MB
    unsigned short* vb  = kb  + (1u << 20);                    // 2 MB
    unsigned short* pkb = vb  + (1u << 20);                    // 1 MB
    unsigned short* pqb = pkb + (1u << 19);                    // 1 MB
    unsigned short* ctx = pqb + (1u << 19);                    // 2 MB
    unsigned short* ffb = qb;  // alias: 8 MB over q,k,v,pk,pq (dead by FF1)

    dim3 blk2(16, 16);
    embed_ln_kernel<<<dim3(TOK), dim3(256), 0, stream>>>(x, am, word_emb, emb_g, emb_b, h);

    for (int l = 0; l < NLAYER; l++) {
        const float* Wq_l = Wq + (size_t)l * HID * HID;
        const float* Wk_l = Wk + (size_t)l * HID * HID;
        const float* Wv_l = Wv + (size_t)l * HID * HID;
        const float* Wo_l = Wo + (size_t)l * HID * HID;
        const float* Wpk_l = Wpk + (size_t)l * HID * HID;
        const float* Wpq_l = Wpq + (size_t)l * HID * HID;
        const float* W1_l = W1 + (size_t)l * HID * FFDIM;
        const float* W2_l = W2 + (size_t)l * FFDIM * HID;

        gemm_t<0, true, false><<<dim3(HID/64, TOK/64), blk2, 0, stream>>>(h, Wq_l, bq + l*HID, qb, TOK, HID, HID);
        gemm_t<0, true, false><<<dim3(HID/64, TOK/64), blk2, 0, stream>>>(h, Wk_l, bk + l*HID, kb, TOK, HID, HID);
        gemm_t<0, true, false><<<dim3(HID/64, TOK/64), blk2, 0, stream>>>(h, Wv_l, bv + l*HID, vb, TOK, HID, HID);
        gemm_t<0, true, false><<<dim3(HID/64, SPAN2/64), blk2, 0, stream>>>(rel_emb, Wpk_l, bpk + l*HID, pkb, SPAN2, HID, HID);
        gemm_t<0, true, false><<<dim3(HID/64, SPAN2/64), blk2, 0, stream>>>(rel_emb, Wpq_l, bpq + l*HID, pqb, SPAN2, HID, HID);

        attn_kernel<<<dim3(SEQ/32, BATCH*NHEAD), blk2, 0, stream>>>(qb, kb, vb, pkb, pqb, am, ctx);

        gemm_t<1, false, false><<<dim3(HID/64, TOK/64), blk2, 0, stream>>>(ctx, Wo_l, bo + l*HID, t1, TOK, HID, HID);
        add_ln_kernel<<<dim3(TOK), dim3(256), 0, stream>>>(t1, ln1g + l*HID, ln1b + l*HID, h);

        gemm_t<0, true, true><<<dim3(FFDIM/64, TOK/64), blk2, 0, stream>>>(h, W1_l, b1 + l*FFDIM, ffb, TOK, FFDIM, HID);
        gemm_t<1, false, false><<<dim3(HID/64, TOK/64), blk2, 0, stream>>>(ffb, W2_l, b2 + l*HID, t1, TOK, HID, FFDIM);
        add_ln_kernel<<<dim3(TOK), dim3(256), 0, stream>>>(t1, ln2g + l*HID, ln2b + l*HID, h);
    }

    float* out_f = (float*)d_out;
    copy_f_kernel<<<dim3(TOK*HID/256), dim3(256), 0, stream>>>(h, out_f, TOK*HID);
    cls_kernel<<<dim3(TOK), dim3(32), 0, stream>>>(h, cls_w, cls_b, out_f + TOK*HID);
}

// Round 5
// 3812.108 us; speedup vs baseline: 2.3759x; 2.3759x over previous
//
#include <hip/hip_runtime.h>
#include <hip/hip_bf16.h>

// Model dims (fixed by the reference)
#define BATCH  4
#define SEQ    512
#define TOK    (BATCH*SEQ)     // 2048
#define HID    512
#define NHEAD  8
#define HEAD   64
#define FFDIM  2048
#define NLAYER 12
#define SPAN2  1024            // 2*SPAN
#define VOCAB  25
#define LNEPS  1e-7f
#define NEG_BIG -3.0e38f

typedef __attribute__((ext_vector_type(8))) short bf16x8;   // 8 bf16 = 4 VGPRs
typedef __attribute__((ext_vector_type(4))) float floatx4;

__device__ __forceinline__ float b2f(unsigned short u) {
    return __uint_as_float(((unsigned int)u) << 16);
}
__device__ __forceinline__ unsigned short f2b(float f) {
    __hip_bfloat16 h = __float2bfloat16(f);
    return *(unsigned short*)&h;
}

// ---------------- block reductions (blockDim = 256, 1-D) ----------------
__device__ __forceinline__ float block_reduce_sum(float v, float* red) {
    int tid = threadIdx.x;
    red[tid] = v; __syncthreads();
    for (int s = 128; s > 0; s >>= 1) { if (tid < s) red[tid] += red[tid + s]; __syncthreads(); }
    float r = red[0]; __syncthreads();
    return r;
}

// ---------------- embedding gather + LN + mask (writes fp32 h and bf16 hb) ----------------
__global__ void embed_ln_kernel(const int* __restrict__ x, const int* __restrict__ am,
                                const float* __restrict__ word_emb,
                                const float* __restrict__ g, const float* __restrict__ bb,
                                float* __restrict__ h, unsigned short* __restrict__ hb) {
    __shared__ float red[256];
    int t = blockIdx.x, tid = threadIdx.x;
    const float* we = word_emb + (size_t)x[t] * HID;
    float v1 = we[tid], v2 = we[tid + 256];
    float mean = block_reduce_sum(v1 + v2, red) * (1.0f / HID);
    float d1 = v1 - mean, d2 = v2 - mean;
    float var = block_reduce_sum(d1 * d1 + d2 * d2, red) * (1.0f / HID);
    float rstd = rsqrtf(var + LNEPS);
    float maskf = (float)am[t];
    size_t base = (size_t)t * HID;
    float o1 = (d1 * rstd * g[tid]       + bb[tid])       * maskf;
    float o2 = (d2 * rstd * g[tid + 256] + bb[tid + 256]) * maskf;
    h[base + tid] = o1;        h[base + tid + 256] = o2;
    hb[base + tid] = f2b(o1);  hb[base + tid + 256] = f2b(o2);
}

// ---------------- residual add + LN (writes h in place + bf16 hb) ----------------
__global__ void add_ln_kernel(const float* __restrict__ tmp,
                              const float* __restrict__ g, const float* __restrict__ bb,
                              float* __restrict__ h, unsigned short* __restrict__ hb) {
    __shared__ float red[256];
    int t = blockIdx.x, tid = threadIdx.x;
    size_t base = (size_t)t * HID;
    float v1 = tmp[base + tid] + h[base + tid];
    float v2 = tmp[base + tid + 256] + h[base + tid + 256];
    float mean = block_reduce_sum(v1 + v2, red) * (1.0f / HID);
    float d1 = v1 - mean, d2 = v2 - mean;
    float var = block_reduce_sum(d1 * d1 + d2 * d2, red) * (1.0f / HID);
    float rstd = rsqrtf(var + LNEPS);
    float o1 = d1 * rstd * g[tid]       + bb[tid];
    float o2 = d2 * rstd * g[tid + 256] + bb[tid + 256];
    h[base + tid] = o1;        h[base + tid + 256] = o2;
    hb[base + tid] = f2b(o1);  hb[base + tid + 256] = f2b(o2);
}

// ---------------- fp32 -> bf16 convert (rel_emb, n multiple of 1024) ----------------
__global__ void cvt_rel_kernel(const float* __restrict__ in, unsigned short* __restrict__ out) {
    int i = (blockIdx.x * 256 + threadIdx.x) * 4;
    float4 v = *(const float4*)(in + i);
    out[i] = f2b(v.x); out[i+1] = f2b(v.y); out[i+2] = f2b(v.z); out[i+3] = f2b(v.w);
}

// ---------------- MFMA GEMM: C[M,N] = A[M,K](bf16) @ B[K,N](fp32 w, inline->bf16) + bias ----------------
// 64x64 tile, 4 waves 2x2, each 32x32 via 2x2x2 mfma_f32_16x16x32_bf16. BK=64.
// Frag reads are contiguous ds_read_b128 (A[m][k] rows, Bs[n][k] = B^T rows).
template<bool OUT_BF16, bool GELU>
__global__ __launch_bounds__(256) void mfma_gemm(
    const unsigned short* __restrict__ A, const float* __restrict__ B,
    const float* __restrict__ bias, void* __restrict__ Cp, int N, int K) {
    __shared__ unsigned short As[64][72];   // [m][k], row stride 144 B (16B-aligned)
    __shared__ unsigned short Bs[64][72];   // [n][k]
    int tid = threadIdx.x;
    int lane = tid & 63, wid = tid >> 6;
    int wm = wid >> 1, wn = wid & 1;
    int row0 = blockIdx.y * 64, col0 = blockIdx.x * 64;
    int m16 = lane & 15, quad = lane >> 4;

    int ar = tid >> 2, ac = (tid & 3) << 4;          // A staging: row, 16 bf16 cols
    int bk = (tid >> 3) << 1, bn = (tid & 7) << 3;   // B staging: k-pair, 8 n cols

    const unsigned short* Ag = A + (size_t)(row0 + ar) * K + ac;
    const float* Bg = B + (size_t)bk * N + col0 + bn;

    floatx4 acc[2][2];
    #pragma unroll
    for (int mi = 0; mi < 2; mi++)
        #pragma unroll
        for (int ni = 0; ni < 2; ni++) acc[mi][ni] = (floatx4){0.f, 0.f, 0.f, 0.f};

    for (int k0 = 0; k0 < K; k0 += 64) {
        // A tile: 64x64 bf16, contiguous 16B writes
        uint4 av0 = *(const uint4*)(Ag + k0);
        uint4 av1 = *(const uint4*)(Ag + k0 + 8);
        // B tile: 2 k-rows x 8 n fp32, convert + transpose into Bs[n][k] as packed dwords
        const float* br0 = Bg + (size_t)k0 * N;
        const float* br1 = br0 + N;
        float4 b00 = *(const float4*)br0, b01 = *(const float4*)(br0 + 4);
        float4 b10 = *(const float4*)br1, b11 = *(const float4*)(br1 + 4);
        *(uint4*)&As[ar][ac] = av0;
        *(uint4*)&As[ar][ac + 8] = av1;
        float lo[8] = {b00.x, b00.y, b00.z, b00.w, b01.x, b01.y, b01.z, b01.w};
        float hi[8] = {b10.x, b10.y, b10.z, b10.w, b11.x, b11.y, b11.z, b11.w};
        #pragma unroll
        for (int i = 0; i < 8; i++) {
            unsigned int p = (unsigned int)f2b(lo[i]) | ((unsigned int)f2b(hi[i]) << 16);
            *(unsigned int*)&Bs[bn + i][bk] = p;
        }
        __syncthreads();
        #pragma unroll
        for (int kk = 0; kk < 2; kk++) {
            bf16x8 a0 = *(const bf16x8*)&As[wm * 32 + m16][kk * 32 + quad * 8];
            bf16x8 a1 = *(const bf16x8*)&As[wm * 32 + 16 + m16][kk * 32 + quad * 8];
            bf16x8 b0 = *(const bf16x8*)&Bs[wn * 32 + m16][kk * 32 + quad * 8];
            bf16x8 b1 = *(const bf16x8*)&Bs[wn * 32 + 16 + m16][kk * 32 + quad * 8];
            acc[0][0] = __builtin_amdgcn_mfma_f32_16x16x32_bf16(a0, b0, acc[0][0], 0, 0, 0);
            acc[0][1] = __builtin_amdgcn_mfma_f32_16x16x32_bf16(a0, b1, acc[0][1], 0, 0, 0);
            acc[1][0] = __builtin_amdgcn_mfma_f32_16x16x32_bf16(a1, b0, acc[1][0], 0, 0, 0);
            acc[1][1] = __builtin_amdgcn_mfma_f32_16x16x32_bf16(a1, b1, acc[1][1], 0, 0, 0);
        }
        __syncthreads();
    }
    // epilogue: D col = lane&15, row = quad*4 + reg  [m89-verified mapping]
    #pragma unroll
    for (int ni = 0; ni < 2; ni++) {
        int colg = col0 + wn * 32 + ni * 16 + m16;
        float bv = bias[colg];
        #pragma unroll
        for (int mi = 0; mi < 2; mi++) {
            #pragma unroll
            for (int r = 0; r < 4; r++) {
                int rowg = row0 + wm * 32 + mi * 16 + quad * 4 + r;
                float v = acc[mi][ni][r] + bv;
                if (GELU) v = 0.5f * v * (1.0f + erff(v * 0.70710678118654752f));
                if (OUT_BF16) ((unsigned short*)Cp)[(size_t)rowg * N + colg] = f2b(v);
                else          ((float*)Cp)[(size_t)rowg * N + colg] = v;
            }
        }
    }
}

// ---------------- fused flash-style disentangled attention ----------------
// s[q,k] = (Q_q.K_k + Q_q.pk[q-k+512] + K_k.pq[q-k+512]) / sqrt(192), online softmax, @V.
// grid (qtile=16, bh=32), block (16,16). All tensor operands are ws bf16.
__global__ __launch_bounds__(256) void attn_kernel(
    const unsigned short* __restrict__ Q, const unsigned short* __restrict__ K,
    const unsigned short* __restrict__ V,
    const unsigned short* __restrict__ PK, const unsigned short* __restrict__ PQ,
    const int* __restrict__ am, unsigned short* __restrict__ ctx) {
    __shared__ float Qs[32][65], Ks[32][65], Vs[32][65];
    __shared__ float PKs[63][65], PQs[63][65];
    __shared__ float Ss[32][33];
    __shared__ float mrow[32], lrow[32], arow[32];
    __shared__ int mkk[32];
    int bh = blockIdx.y, b = bh >> 3, hh = bh & 7;
    int q0 = blockIdx.x * 32;
    int tid = threadIdx.y * 16 + threadIdx.x;
    const float inv_scale = 0.07216878364870323f; // 1/sqrt(192)

    {   // Q tile 32x64
        int r = tid >> 3, c = (tid & 7) * 8;
        const unsigned short* qp = Q + ((size_t)(b * SEQ + q0 + r) * HID) + hh * HEAD + c;
        ushort4 a = *(const ushort4*)qp, a2 = *(const ushort4*)(qp + 4);
        Qs[r][c] = b2f(a.x); Qs[r][c+1] = b2f(a.y); Qs[r][c+2] = b2f(a.z); Qs[r][c+3] = b2f(a.w);
        Qs[r][c+4] = b2f(a2.x); Qs[r][c+5] = b2f(a2.y); Qs[r][c+6] = b2f(a2.z); Qs[r][c+7] = b2f(a2.w);
    }
    if (tid < 32) { mrow[tid] = NEG_BIG; lrow[tid] = 0.0f; }
    float acc0[4] = {}, acc1[4] = {};
    int rowA = threadIdx.y * 2, dA = threadIdx.x * 4;

    for (int k0 = 0; k0 < SEQ; k0 += 32) {
        __syncthreads();
        {   // K, V tiles 32x64
            int r = tid >> 3, c = (tid & 7) * 8;
            const unsigned short* kp = K + ((size_t)(b * SEQ + k0 + r) * HID) + hh * HEAD + c;
            ushort4 a = *(const ushort4*)kp, a2 = *(const ushort4*)(kp + 4);
            Ks[r][c] = b2f(a.x); Ks[r][c+1] = b2f(a.y); Ks[r][c+2] = b2f(a.z); Ks[r][c+3] = b2f(a.w);
            Ks[r][c+4] = b2f(a2.x); Ks[r][c+5] = b2f(a2.y); Ks[r][c+6] = b2f(a2.z); Ks[r][c+7] = b2f(a2.w);
            const unsigned short* vp = V + ((size_t)(b * SEQ + k0 + r) * HID) + hh * HEAD + c;
            ushort4 e = *(const ushort4*)vp, e2 = *(const ushort4*)(vp + 4);
            Vs[r][c] = b2f(e.x); Vs[r][c+1] = b2f(e.y); Vs[r][c+2] = b2f(e.z); Vs[r][c+3] = b2f(e.w);
            Vs[r][c+4] = b2f(e2.x); Vs[r][c+5] = b2f(e2.y); Vs[r][c+6] = b2f(e2.z); Vs[r][c+7] = b2f(e2.w);
        }
        int d0 = q0 - k0 + 481;  // window base in [1,961]; +62 <= 1023, no clamp binds
        for (int idx = tid; idx < 63 * 8; idx += 256) {
            int r = idx >> 3, c = (idx & 7) * 8;
            const unsigned short* pkp = PK + (size_t)(d0 + r) * HID + hh * HEAD + c;
            ushort4 a = *(const ushort4*)pkp, a2 = *(const ushort4*)(pkp + 4);
            PKs[r][c] = b2f(a.x); PKs[r][c+1] = b2f(a.y); PKs[r][c+2] = b2f(a.z); PKs[r][c+3] = b2f(a.w);
            PKs[r][c+4] = b2f(a2.x); PKs[r][c+5] = b2f(a2.y); PKs[r][c+6] = b2f(a2.z); PKs[r][c+7] = b2f(a2.w);
            const unsigned short* pqp = PQ + (size_t)(d0 + r) * HID + hh * HEAD + c;
            ushort4 e = *(const ushort4*)pqp, e2 = *(const ushort4*)(pqp + 4);
            PQs[r][c] = b2f(e.x); PQs[r][c+1] = b2f(e.y); PQs[r][c+2] = b2f(e.z); PQs[r][c+3] = b2f(e.w);
            PQs[r][c+4] = b2f(e2.x); PQs[r][c+5] = b2f(e2.y); PQs[r][c+6] = b2f(e2.z); PQs[r][c+7] = b2f(e2.w);
        }
        if (tid < 32) mkk[tid] = am[b * SEQ + k0 + tid];
        __syncthreads();

        {   // scores 2x2 per thread
            int qq0 = threadIdx.y * 2, kk0 = threadIdx.x * 2;
            int dr = qq0 - kk0 + 31;   // in [1,61]
            float s00 = 0, s01 = 0, s10 = 0, s11 = 0;
            #pragma unroll 8
            for (int d = 0; d < 64; d++) {
                float q0v = Qs[qq0][d],     q1v = Qs[qq0 + 1][d];
                float k0v = Ks[kk0][d],     k1v = Ks[kk0 + 1][d];
                float pkm = PKs[dr - 1][d], pk0 = PKs[dr][d], pkp = PKs[dr + 1][d];
                float pqm = PQs[dr - 1][d], pq0 = PQs[dr][d], pqp = PQs[dr + 1][d];
                s00 += q0v * (k0v + pk0) + k0v * pq0;
                s01 += q0v * (k1v + pkm) + k1v * pqm;
                s10 += q1v * (k0v + pkp) + k0v * pqp;
                s11 += q1v * (k1v + pk0) + k1v * pq0;
            }
            Ss[qq0][kk0]         = s00 * inv_scale;
            Ss[qq0][kk0 + 1]     = s01 * inv_scale;
            Ss[qq0 + 1][kk0]     = s10 * inv_scale;
            Ss[qq0 + 1][kk0 + 1] = s11 * inv_scale;
        }
        __syncthreads();

        {   // online softmax: row r, 4 cols per thread, 8 threads/row
            int r = tid >> 3, cg = (tid & 7) * 4;
            float sv[4]; float tmax = NEG_BIG;
            #pragma unroll
            for (int j = 0; j < 4; j++) {
                sv[j] = mkk[cg + j] ? Ss[r][cg + j] : NEG_BIG;
                tmax = fmaxf(tmax, sv[j]);
            }
            tmax = fmaxf(tmax, __shfl_xor(tmax, 1));
            tmax = fmaxf(tmax, __shfl_xor(tmax, 2));
            tmax = fmaxf(tmax, __shfl_xor(tmax, 4));
            float mold = mrow[r];
            float mnew = fmaxf(mold, tmax);
            float psum = 0.0f;
            #pragma unroll
            for (int j = 0; j < 4; j++) {
                float p = (sv[j] > -1.5e38f) ? __expf(sv[j] - mnew) : 0.0f;
                Ss[r][cg + j] = p;
                psum += p;
            }
            psum += __shfl_xor(psum, 1);
            psum += __shfl_xor(psum, 2);
            psum += __shfl_xor(psum, 4);
            if ((tid & 7) == 0) {
                float alpha = __expf(mold - mnew);
                mrow[r] = mnew;
                lrow[r] = lrow[r] * alpha + psum;
                arow[r] = alpha;
            }
        }
        __syncthreads();

        {   // acc update: 2 rows x 4 d per thread
            float a0 = arow[rowA], a1 = arow[rowA + 1];
            #pragma unroll
            for (int j = 0; j < 4; j++) { acc0[j] *= a0; acc1[j] *= a1; }
            #pragma unroll 8
            for (int kk = 0; kk < 32; kk++) {
                float p0 = Ss[rowA][kk], p1 = Ss[rowA + 1][kk];
                #pragma unroll
                for (int j = 0; j < 4; j++) {
                    float vv = Vs[kk][dA + j];
                    acc0[j] += p0 * vv;
                    acc1[j] += p1 * vv;
                }
            }
        }
    }
    // epilogue
    float l0 = lrow[rowA], l1 = lrow[rowA + 1];
    float inv0 = l0 > 0.0f ? 1.0f / l0 : 0.0f;
    float inv1 = l1 > 0.0f ? 1.0f / l1 : 0.0f;
    inv0 *= (float)am[b * SEQ + q0 + rowA];
    inv1 *= (float)am[b * SEQ + q0 + rowA + 1];
    size_t base0 = ((size_t)(b * SEQ + q0 + rowA) * HID) + hh * HEAD + dA;
    size_t base1 = base0 + HID;
    #pragma unroll
    for (int j = 0; j < 4; j++) {
        ctx[base0 + j] = f2b(acc0[j] * inv0);
        ctx[base1 + j] = f2b(acc1[j] * inv1);
    }
}

// ---------------- output copy / classifier (fp32 out) ----------------
__global__ void copy_f_kernel(const float* __restrict__ in, float* __restrict__ out, int n) {
    int i = blockIdx.x * 256 + threadIdx.x;
    if (i < n) out[i] = in[i];
}
__global__ void cls_kernel(const float* __restrict__ h, const float* __restrict__ cls_w,
                           const float* __restrict__ cls_b, float* __restrict__ out) {
    int t = blockIdx.x, v = threadIdx.x;
    if (v < VOCAB) {
        const float* hr = h + (size_t)t * HID;
        const float* wr = cls_w + (size_t)v * HID;
        float acc = cls_b[v];
        for (int d = 0; d < HID; d++) acc += hr[d] * wr[d];
        out[t * VOCAB + v] = acc;
    }
}

extern "C" void kernel_launch(void* const* d_in, const int* in_sizes, int n_in,
                              void* d_out, int out_size, void* d_ws, size_t ws_size,
                              hipStream_t stream) {
    const int* x     = (const int*)d_in[0];
    const int* am    = (const int*)d_in[1];
    const float* word_emb = (const float*)d_in[2];
    const float* emb_g    = (const float*)d_in[3];
    const float* emb_b    = (const float*)d_in[4];
    const float* rel_emb  = (const float*)d_in[5];
    const float* Wq  = (const float*)d_in[6];  const float* bq  = (const float*)d_in[7];
    const float* Wk  = (const float*)d_in[8];  const float* bk  = (const float*)d_in[9];
    const float* Wv  = (const float*)d_in[10]; const float* bv  = (const float*)d_in[11];
    const float* Wpk = (const float*)d_in[12]; const float* bpk = (const float*)d_in[13];
    const float* Wpq = (const float*)d_in[14]; const float* bpq = (const float*)d_in[15];
    const float* Wo  = (const float*)d_in[16]; const float* bo  = (const float*)d_in[17];
    const float* ln1g = (const float*)d_in[18]; const float* ln1b = (const float*)d_in[19];
    const float* W1  = (const float*)d_in[20]; const float* b1  = (const float*)d_in[21];
    const float* W2  = (const float*)d_in[22]; const float* b2  = (const float*)d_in[23];
    const float* ln2g = (const float*)d_in[24]; const float* ln2b = (const float*)d_in[25];
    const float* cls_w = (const float*)d_in[26]; const float* cls_b = (const float*)d_in[27];

    // ---- workspace layout: exactly 19 MB (proven available in R3/R4) ----
    // [0,4M)  h fp32 | [4M,8M) t1 fp32 | [8M,16M) qb|kb|vb|pkb|pqb bf16 (ffb alias)
    // [16M,17M) relb bf16 | [17M,19M) hb bf16 (ctx alias; disjoint lifetimes)
    const size_t NEEDED = 19u << 20;
    if (ws_size < NEEDED) return;  // signal: zero-output signature => ws too small
    char* wsb = (char*)d_ws;
    float* h  = (float*)wsb;                                   // 4 MB
    float* t1 = (float*)(wsb + (4u << 20));                    // 4 MB
    unsigned short* qb   = (unsigned short*)(wsb + (8u << 20)); // 2 MB
    unsigned short* kb   = qb  + (1u << 20);                   // 2 MB
    unsigned short* vb   = kb  + (1u << 20);                   // 2 MB
    unsigned short* pkb  = vb  + (1u << 20);                   // 1 MB
    unsigned short* pqb  = pkb + (1u << 19);                   // 1 MB
    unsigned short* relb = (unsigned short*)(wsb + (16u << 20)); // 1 MB
    unsigned short* hb   = (unsigned short*)(wsb + (17u << 20)); // 2 MB
    unsigned short* ctx  = hb;   // alias: hb dead between V-GEMM and add_ln1
    unsigned short* ffb  = qb;   // alias: 8 MB over q,k,v,pk,pq (dead by FF1)

    cvt_rel_kernel<<<dim3(SPAN2 * HID / 1024), dim3(256), 0, stream>>>(rel_emb, relb);
    embed_ln_kernel<<<dim3(TOK), dim3(256), 0, stream>>>(x, am, word_emb, emb_g, emb_b, h, hb);

    for (int l = 0; l < NLAYER; l++) {
        const float* Wq_l = Wq + (size_t)l * HID * HID;
        const float* Wk_l = Wk + (size_t)l * HID * HID;
        const float* Wv_l = Wv + (size_t)l * HID * HID;
        const float* Wo_l = Wo + (size_t)l * HID * HID;
        const float* Wpk_l = Wpk + (size_t)l * HID * HID;
        const float* Wpq_l = Wpq + (size_t)l * HID * HID;
        const float* W1_l = W1 + (size_t)l * HID * FFDIM;
        const float* W2_l = W2 + (size_t)l * FFDIM * HID;

        mfma_gemm<true,  false><<<dim3(HID/64, TOK/64),   dim3(256), 0, stream>>>(hb,   Wq_l,  bq + l*HID,  qb,  HID, HID);
        mfma_gemm<true,  false><<<dim3(HID/64, TOK/64),   dim3(256), 0, stream>>>(hb,   Wk_l,  bk + l*HID,  kb,  HID, HID);
        mfma_gemm<true,  false><<<dim3(HID/64, TOK/64),   dim3(256), 0, stream>>>(hb,   Wv_l,  bv + l*HID,  vb,  HID, HID);
        mfma_gemm<true,  false><<<dim3(HID/64, SPAN2/64), dim3(256), 0, stream>>>(relb, Wpk_l, bpk + l*HID, pkb, HID, HID);
        mfma_gemm<true,  false><<<dim3(HID/64, SPAN2/64), dim3(256), 0, stream>>>(relb, Wpq_l, bpq + l*HID, pqb, HID, HID);

        attn_kernel<<<dim3(SEQ/32, BATCH*NHEAD), dim3(16, 16), 0, stream>>>(qb, kb, vb, pkb, pqb, am, ctx);

        mfma_gemm<false, false><<<dim3(HID/64, TOK/64),   dim3(256), 0, stream>>>(ctx,  Wo_l,  bo + l*HID,  t1,  HID, HID);
        add_ln_kernel<<<dim3(TOK), dim3(256), 0, stream>>>(t1, ln1g + l*HID, ln1b + l*HID, h, hb);

        mfma_gemm<true,  true ><<<dim3(FFDIM/64, TOK/64), dim3(256), 0, stream>>>(hb,   W1_l,  b1 + l*FFDIM, ffb, FFDIM, HID);
        mfma_gemm<false, false><<<dim3(HID/64, TOK/64),   dim3(256), 0, stream>>>(ffb,  W2_l,  b2 + l*HID,  t1,  HID, FFDIM);
        add_ln_kernel<<<dim3(TOK), dim3(256), 0, stream>>>(t1, ln2g + l*HID, ln2b + l*HID, h, hb);
    }

    float* out_f = (float*)d_out;
    copy_f_kernel<<<dim3(TOK*HID/256), dim3(256), 0, stream>>>(h, out_f, TOK*HID);
    cls_kernel<<<dim3(TOK), dim3(32), 0, stream>>>(h, cls_w, cls_b, out_f + TOK*HID);
}

// Round 6
// 2369.191 us; speedup vs baseline: 3.8230x; 1.6090x over previous
//
#include <hip/hip_runtime.h>
#include <hip/hip_bf16.h>

// Model dims (fixed by the reference)
#define BATCH  4
#define SEQ    512
#define TOK    (BATCH*SEQ)     // 2048
#define HID    512
#define NHEAD  8
#define HEAD   64
#define FFDIM  2048
#define NLAYER 12
#define SPAN2  1024            // 2*SPAN
#define VOCAB  25
#define LNEPS  1e-7f
#define NEG_BIG -3.0e38f

typedef __attribute__((ext_vector_type(8))) short bf16x8;   // 8 bf16 = 4 VGPRs
typedef __attribute__((ext_vector_type(4))) float floatx4;

#define MFMA16(a, b, c) __builtin_amdgcn_mfma_f32_16x16x32_bf16((a), (b), (c), 0, 0, 0)

__device__ __forceinline__ float b2f(unsigned short u) {
    return __uint_as_float(((unsigned int)u) << 16);
}
__device__ __forceinline__ unsigned short f2b(float f) {
    __hip_bfloat16 h = __float2bfloat16(f);
    return *(unsigned short*)&h;
}

// ---------------- block reductions (blockDim = 256, 1-D) ----------------
__device__ __forceinline__ float block_reduce_sum(float v, float* red) {
    int tid = threadIdx.x;
    red[tid] = v; __syncthreads();
    for (int s = 128; s > 0; s >>= 1) { if (tid < s) red[tid] += red[tid + s]; __syncthreads(); }
    float r = red[0]; __syncthreads();
    return r;
}

// ---------------- embedding gather + LN + mask (writes fp32 h and bf16 hb) ----------------
__global__ void embed_ln_kernel(const int* __restrict__ x, const int* __restrict__ am,
                                const float* __restrict__ word_emb,
                                const float* __restrict__ g, const float* __restrict__ bb,
                                float* __restrict__ h, unsigned short* __restrict__ hb) {
    __shared__ float red[256];
    int t = blockIdx.x, tid = threadIdx.x;
    const float* we = word_emb + (size_t)x[t] * HID;
    float v1 = we[tid], v2 = we[tid + 256];
    float mean = block_reduce_sum(v1 + v2, red) * (1.0f / HID);
    float d1 = v1 - mean, d2 = v2 - mean;
    float var = block_reduce_sum(d1 * d1 + d2 * d2, red) * (1.0f / HID);
    float rstd = rsqrtf(var + LNEPS);
    float maskf = (float)am[t];
    size_t base = (size_t)t * HID;
    float o1 = (d1 * rstd * g[tid]       + bb[tid])       * maskf;
    float o2 = (d2 * rstd * g[tid + 256] + bb[tid + 256]) * maskf;
    h[base + tid] = o1;        h[base + tid + 256] = o2;
    hb[base + tid] = f2b(o1);  hb[base + tid + 256] = f2b(o2);
}

// ---------------- residual add + LN (writes h in place + bf16 hb) ----------------
__global__ void add_ln_kernel(const float* __restrict__ tmp,
                              const float* __restrict__ g, const float* __restrict__ bb,
                              float* __restrict__ h, unsigned short* __restrict__ hb) {
    __shared__ float red[256];
    int t = blockIdx.x, tid = threadIdx.x;
    size_t base = (size_t)t * HID;
    float v1 = tmp[base + tid] + h[base + tid];
    float v2 = tmp[base + tid + 256] + h[base + tid + 256];
    float mean = block_reduce_sum(v1 + v2, red) * (1.0f / HID);
    float d1 = v1 - mean, d2 = v2 - mean;
    float var = block_reduce_sum(d1 * d1 + d2 * d2, red) * (1.0f / HID);
    float rstd = rsqrtf(var + LNEPS);
    float o1 = d1 * rstd * g[tid]       + bb[tid];
    float o2 = d2 * rstd * g[tid + 256] + bb[tid + 256];
    h[base + tid] = o1;        h[base + tid + 256] = o2;
    hb[base + tid] = f2b(o1);  hb[base + tid + 256] = f2b(o2);
}

// ---------------- fp32 -> bf16 convert (rel_emb, n multiple of 1024) ----------------
__global__ void cvt_rel_kernel(const float* __restrict__ in, unsigned short* __restrict__ out) {
    int i = (blockIdx.x * 256 + threadIdx.x) * 4;
    float4 v = *(const float4*)(in + i);
    out[i] = f2b(v.x); out[i+1] = f2b(v.y); out[i+2] = f2b(v.z); out[i+3] = f2b(v.w);
}

// ---------------- MFMA GEMM: C[M,N] = A[M,K](bf16) @ B[K,N](fp32 w, inline->bf16) + bias ----------------
// 64x64 tile, 4 waves 2x2, each 32x32 via 2x2x2 mfma_f32_16x16x32_bf16. BK=64.
template<bool OUT_BF16, bool GELU>
__global__ __launch_bounds__(256) void mfma_gemm(
    const unsigned short* __restrict__ A, const float* __restrict__ B,
    const float* __restrict__ bias, void* __restrict__ Cp, int N, int K) {
    __shared__ unsigned short As[64][72];   // [m][k]
    __shared__ unsigned short Bs[64][72];   // [n][k]
    int tid = threadIdx.x;
    int lane = tid & 63, wid = tid >> 6;
    int wm = wid >> 1, wn = wid & 1;
    int row0 = blockIdx.y * 64, col0 = blockIdx.x * 64;
    int m16 = lane & 15, quad = lane >> 4;

    int ar = tid >> 2, ac = (tid & 3) << 4;          // A staging: row, 16 bf16 cols
    int bk = (tid >> 3) << 1, bn = (tid & 7) << 3;   // B staging: k-pair, 8 n cols

    const unsigned short* Ag = A + (size_t)(row0 + ar) * K + ac;
    const float* Bg = B + (size_t)bk * N + col0 + bn;

    floatx4 acc[2][2];
    #pragma unroll
    for (int mi = 0; mi < 2; mi++)
        #pragma unroll
        for (int ni = 0; ni < 2; ni++) acc[mi][ni] = (floatx4){0.f, 0.f, 0.f, 0.f};

    for (int k0 = 0; k0 < K; k0 += 64) {
        uint4 av0 = *(const uint4*)(Ag + k0);
        uint4 av1 = *(const uint4*)(Ag + k0 + 8);
        const float* br0 = Bg + (size_t)k0 * N;
        const float* br1 = br0 + N;
        float4 b00 = *(const float4*)br0, b01 = *(const float4*)(br0 + 4);
        float4 b10 = *(const float4*)br1, b11 = *(const float4*)(br1 + 4);
        *(uint4*)&As[ar][ac] = av0;
        *(uint4*)&As[ar][ac + 8] = av1;
        float lo[8] = {b00.x, b00.y, b00.z, b00.w, b01.x, b01.y, b01.z, b01.w};
        float hi[8] = {b10.x, b10.y, b10.z, b10.w, b11.x, b11.y, b11.z, b11.w};
        #pragma unroll
        for (int i = 0; i < 8; i++) {
            unsigned int p = (unsigned int)f2b(lo[i]) | ((unsigned int)f2b(hi[i]) << 16);
            *(unsigned int*)&Bs[bn + i][bk] = p;
        }
        __syncthreads();
        #pragma unroll
        for (int kk = 0; kk < 2; kk++) {
            bf16x8 a0 = *(const bf16x8*)&As[wm * 32 + m16][kk * 32 + quad * 8];
            bf16x8 a1 = *(const bf16x8*)&As[wm * 32 + 16 + m16][kk * 32 + quad * 8];
            bf16x8 b0 = *(const bf16x8*)&Bs[wn * 32 + m16][kk * 32 + quad * 8];
            bf16x8 b1 = *(const bf16x8*)&Bs[wn * 32 + 16 + m16][kk * 32 + quad * 8];
            acc[0][0] = MFMA16(a0, b0, acc[0][0]);
            acc[0][1] = MFMA16(a0, b1, acc[0][1]);
            acc[1][0] = MFMA16(a1, b0, acc[1][0]);
            acc[1][1] = MFMA16(a1, b1, acc[1][1]);
        }
        __syncthreads();
    }
    #pragma unroll
    for (int ni = 0; ni < 2; ni++) {
        int colg = col0 + wn * 32 + ni * 16 + m16;
        float bv = bias[colg];
        #pragma unroll
        for (int mi = 0; mi < 2; mi++) {
            #pragma unroll
            for (int r = 0; r < 4; r++) {
                int rowg = row0 + wm * 32 + mi * 16 + quad * 4 + r;
                float v = acc[mi][ni][r] + bv;
                if (GELU) v = 0.5f * v * (1.0f + erff(v * 0.70710678118654752f));
                if (OUT_BF16) ((unsigned short*)Cp)[(size_t)rowg * N + colg] = f2b(v);
                else          ((float*)Cp)[(size_t)rowg * N + colg] = v;
            }
        }
    }
}

// ---------------- MFMA fused flash-style disentangled attention ----------------
// s[q,k] = (Q_q.K_k + Q_q.pk[q-k+512] + K_k.pq[q-k+512]) / sqrt(192), online softmax, @V.
// grid (qtile=16, bh=32), block 256 = 4 waves. q-tile 32, k-tile 32.
// Per k-tile: S = Q@K^T (MFMA), A = Q@PKw^T (MFMA), Bw = K@PQw^T (MFMA),
// diagonal gather j = qq-kk+31, online softmax (VALU), O += P@V (MFMA, V transposed in LDS).
__global__ __launch_bounds__(256) void attn_kernel(
    const unsigned short* __restrict__ Q, const unsigned short* __restrict__ K,
    const unsigned short* __restrict__ V,
    const unsigned short* __restrict__ PK, const unsigned short* __restrict__ PQ,
    const int* __restrict__ am, unsigned short* __restrict__ ctx) {
    __shared__ unsigned short Qs[32][72], Ks[32][72];
    __shared__ unsigned short PKw[64][72], PQw[64][72];
    __shared__ unsigned short Vt[64][40];     // [d][kk]
    __shared__ unsigned short Pls[32][40];    // [q][kk] bf16 probs
    __shared__ float Afs[32][65];             // [q][j]  stride 65
    __shared__ float Bfs[32][66];             // [k][j]  stride 66 (banded gather de-conflict)
    __shared__ float Scomb[32][33];
    __shared__ float mrow[32], lrow[32], arow[32];
    __shared__ int mkk[32], mq[32];

    int bh = blockIdx.y, b = bh >> 3, hh = bh & 7;
    int q0 = blockIdx.x * 32;
    int tid = threadIdx.x;
    int lane = tid & 63, wave = tid >> 6;
    int quad = lane >> 4, m16 = lane & 15;
    int qt = wave >> 1, kt = wave & 1;        // S-quadrant assignment
    const float inv_scale = 0.07216878364870323f; // 1/sqrt(192)

    {   // Q tile 32x64 (once)
        int r = tid >> 3, c = (tid & 7) * 8;
        *(uint4*)&Qs[r][c] = *(const uint4*)(Q + (size_t)(b * SEQ + q0 + r) * HID + hh * HEAD + c);
        if (tid < 32) { mrow[tid] = NEG_BIG; lrow[tid] = 0.0f; mq[tid] = am[b * SEQ + q0 + tid]; }
    }
    floatx4 accO[2];
    accO[0] = (floatx4){0.f, 0.f, 0.f, 0.f};
    accO[1] = (floatx4){0.f, 0.f, 0.f, 0.f};

    for (int k0 = 0; k0 < SEQ; k0 += 32) {
        __syncthreads();   // prior PV / gather reads complete before restaging
        {   // stage K (rows), V (transposed), PKw/PQw window
            int r = tid >> 3, c = (tid & 7) * 8;
            *(uint4*)&Ks[r][c] = *(const uint4*)(K + (size_t)(b * SEQ + k0 + r) * HID + hh * HEAD + c);
            uint4 vv = *(const uint4*)(V + (size_t)(b * SEQ + k0 + r) * HID + hh * HEAD + c);
            unsigned short* vp = (unsigned short*)&vv;
            #pragma unroll
            for (int j = 0; j < 8; j++) Vt[c + j][r] = vp[j];
            int d0 = q0 - k0 + 481;   // window base in [1,961]
            #pragma unroll
            for (int i = 0; i < 2; i++) {
                int rr = r + i * 32;
                int row = d0 + rr; row = row > 1023 ? 1023 : row;  // row 63 pad never gathered
                *(uint4*)&PKw[rr][c] = *(const uint4*)(PK + (size_t)row * HID + hh * HEAD + c);
                *(uint4*)&PQw[rr][c] = *(const uint4*)(PQ + (size_t)row * HID + hh * HEAD + c);
            }
            if (tid < 32) mkk[tid] = am[b * SEQ + k0 + tid];
        }
        __syncthreads();

        // ---- MFMA phase: S quadrant + A columns + Bw columns ----
        floatx4 accA0 = (floatx4){0.f,0.f,0.f,0.f}, accA1 = (floatx4){0.f,0.f,0.f,0.f};
        floatx4 accB0 = (floatx4){0.f,0.f,0.f,0.f}, accB1 = (floatx4){0.f,0.f,0.f,0.f};
        floatx4 accS  = (floatx4){0.f,0.f,0.f,0.f};
        #pragma unroll
        for (int ks = 0; ks < 2; ks++) {
            int co = ks * 32 + quad * 8;
            bf16x8 qf0 = *(const bf16x8*)&Qs[m16][co];
            bf16x8 qf1 = *(const bf16x8*)&Qs[16 + m16][co];
            bf16x8 kf0 = *(const bf16x8*)&Ks[m16][co];
            bf16x8 kf1 = *(const bf16x8*)&Ks[16 + m16][co];
            bf16x8 pkf = *(const bf16x8*)&PKw[wave * 16 + m16][co];
            bf16x8 pqf = *(const bf16x8*)&PQw[wave * 16 + m16][co];
            accA0 = MFMA16(qf0, pkf, accA0);
            accA1 = MFMA16(qf1, pkf, accA1);
            accB0 = MFMA16(kf0, pqf, accB0);
            accB1 = MFMA16(kf1, pqf, accB1);
            accS  = MFMA16(qt ? qf1 : qf0, kt ? kf1 : kf0, accS);
        }
        #pragma unroll
        for (int r = 0; r < 4; r++) {   // D: row = quad*4+r, col = wave*16+m16
            Afs[quad * 4 + r][wave * 16 + m16]      = accA0[r];
            Afs[16 + quad * 4 + r][wave * 16 + m16] = accA1[r];
            Bfs[quad * 4 + r][wave * 16 + m16]      = accB0[r];
            Bfs[16 + quad * 4 + r][wave * 16 + m16] = accB1[r];
        }
        __syncthreads();

        {   // combine: scores + banded gather
            int kc = kt * 16 + m16;
            #pragma unroll
            for (int r = 0; r < 4; r++) {
                int qq = qt * 16 + quad * 4 + r;
                int j = qq - kc + 31;            // in [0,62]
                Scomb[qq][kc] = (accS[r] + Afs[qq][j] + Bfs[kc][j]) * inv_scale;
            }
        }
        __syncthreads();

        {   // online softmax: row r, 4 cols/thread, 8 threads/row; P rounded to bf16, l from rounded p
            int r = tid >> 3, cg = (tid & 7) * 4;
            float sv[4]; float tmax = NEG_BIG;
            #pragma unroll
            for (int j = 0; j < 4; j++) {
                sv[j] = mkk[cg + j] ? Scomb[r][cg + j] : NEG_BIG;
                tmax = fmaxf(tmax, sv[j]);
            }
            tmax = fmaxf(tmax, __shfl_xor(tmax, 1));
            tmax = fmaxf(tmax, __shfl_xor(tmax, 2));
            tmax = fmaxf(tmax, __shfl_xor(tmax, 4));
            float mold = mrow[r];
            float mnew = fmaxf(mold, tmax);
            float psum = 0.0f;
            #pragma unroll
            for (int j = 0; j < 4; j++) {
                float p = (sv[j] > -1.5e38f) ? __expf(sv[j] - mnew) : 0.0f;
                unsigned short pb = f2b(p);
                Pls[r][cg + j] = pb;
                psum += b2f(pb);                 // consistent with PV operand
            }
            psum += __shfl_xor(psum, 1);
            psum += __shfl_xor(psum, 2);
            psum += __shfl_xor(psum, 4);
            if ((tid & 7) == 0) {
                float alpha = __expf(mold - mnew);
                mrow[r] = mnew;
                lrow[r] = lrow[r] * alpha + psum;
                arow[r] = alpha;
            }
        }
        __syncthreads();

        {   // O rescale + PV MFMA (wave owns d-cols wave*16+m16)
            #pragma unroll
            for (int q2 = 0; q2 < 2; q2++) {
                #pragma unroll
                for (int r = 0; r < 4; r++) accO[q2][r] *= arow[q2 * 16 + quad * 4 + r];
            }
            bf16x8 pf0 = *(const bf16x8*)&Pls[m16][quad * 8];
            bf16x8 pf1 = *(const bf16x8*)&Pls[16 + m16][quad * 8];
            bf16x8 vf  = *(const bf16x8*)&Vt[wave * 16 + m16][quad * 8];
            accO[0] = MFMA16(pf0, vf, accO[0]);
            accO[1] = MFMA16(pf1, vf, accO[1]);
        }
    }
    __syncthreads();
    // epilogue: O[q][d] / l, query mask, write bf16 ctx
    #pragma unroll
    for (int q2 = 0; q2 < 2; q2++) {
        #pragma unroll
        for (int r = 0; r < 4; r++) {
            int qq = q2 * 16 + quad * 4 + r;
            float l = lrow[qq];
            float inv = l > 0.0f ? 1.0f / l : 0.0f;
            inv *= (float)mq[qq];
            ctx[(size_t)(b * SEQ + q0 + qq) * HID + hh * HEAD + wave * 16 + m16] = f2b(accO[q2][r] * inv);
        }
    }
}

// ---------------- output copy / classifier (fp32 out) ----------------
__global__ void copy_f_kernel(const float* __restrict__ in, float* __restrict__ out, int n) {
    int i = blockIdx.x * 256 + threadIdx.x;
    if (i < n) out[i] = in[i];
}
__global__ void cls_kernel(const float* __restrict__ h, const float* __restrict__ cls_w,
                           const float* __restrict__ cls_b, float* __restrict__ out) {
    int t = blockIdx.x, v = threadIdx.x;
    if (v < VOCAB) {
        const float* hr = h + (size_t)t * HID;
        const float* wr = cls_w + (size_t)v * HID;
        float acc = cls_b[v];
        for (int d = 0; d < HID; d++) acc += hr[d] * wr[d];
        out[t * VOCAB + v] = acc;
    }
}

extern "C" void kernel_launch(void* const* d_in, const int* in_sizes, int n_in,
                              void* d_out, int out_size, void* d_ws, size_t ws_size,
                              hipStream_t stream) {
    const int* x     = (const int*)d_in[0];
    const int* am    = (const int*)d_in[1];
    const float* word_emb = (const float*)d_in[2];
    const float* emb_g    = (const float*)d_in[3];
    const float* emb_b    = (const float*)d_in[4];
    const float* rel_emb  = (const float*)d_in[5];
    const float* Wq  = (const float*)d_in[6];  const float* bq  = (const float*)d_in[7];
    const float* Wk  = (const float*)d_in[8];  const float* bk  = (const float*)d_in[9];
    const float* Wv  = (const float*)d_in[10]; const float* bv  = (const float*)d_in[11];
    const float* Wpk = (const float*)d_in[12]; const float* bpk = (const float*)d_in[13];
    const float* Wpq = (const float*)d_in[14]; const float* bpq = (const float*)d_in[15];
    const float* Wo  = (const float*)d_in[16]; const float* bo  = (const float*)d_in[17];
    const float* ln1g = (const float*)d_in[18]; const float* ln1b = (const float*)d_in[19];
    const float* W1  = (const float*)d_in[20]; const float* b1  = (const float*)d_in[21];
    const float* W2  = (const float*)d_in[22]; const float* b2  = (const float*)d_in[23];
    const float* ln2g = (const float*)d_in[24]; const float* ln2b = (const float*)d_in[25];
    const float* cls_w = (const float*)d_in[26]; const float* cls_b = (const float*)d_in[27];

    // ---- workspace layout: exactly 19 MB (proven available) ----
    const size_t NEEDED = 19u << 20;
    if (ws_size < NEEDED) return;
    char* wsb = (char*)d_ws;
    float* h  = (float*)wsb;                                     // 4 MB
    float* t1 = (float*)(wsb + (4u << 20));                      // 4 MB
    unsigned short* qb   = (unsigned short*)(wsb + (8u << 20));  // 2 MB
    unsigned short* kb   = qb  + (1u << 20);                     // 2 MB
    unsigned short* vb   = kb  + (1u << 20);                     // 2 MB
    unsigned short* pkb  = vb  + (1u << 20);                     // 1 MB
    unsigned short* pqb  = pkb + (1u << 19);                     // 1 MB
    unsigned short* relb = (unsigned short*)(wsb + (16u << 20)); // 1 MB
    unsigned short* hb   = (unsigned short*)(wsb + (17u << 20)); // 2 MB
    unsigned short* ctx  = hb;   // alias: hb dead between V-GEMM and add_ln1
    unsigned short* ffb  = qb;   // alias: q..pq dead by FF1

    cvt_rel_kernel<<<dim3(SPAN2 * HID / 1024), dim3(256), 0, stream>>>(rel_emb, relb);
    embed_ln_kernel<<<dim3(TOK), dim3(256), 0, stream>>>(x, am, word_emb, emb_g, emb_b, h, hb);

    for (int l = 0; l < NLAYER; l++) {
        const float* Wq_l = Wq + (size_t)l * HID * HID;
        const float* Wk_l = Wk + (size_t)l * HID * HID;
        const float* Wv_l = Wv + (size_t)l * HID * HID;
        const float* Wo_l = Wo + (size_t)l * HID * HID;
        const float* Wpk_l = Wpk + (size_t)l * HID * HID;
        const float* Wpq_l = Wpq + (size_t)l * HID * HID;
        const float* W1_l = W1 + (size_t)l * HID * FFDIM;
        const float* W2_l = W2 + (size_t)l * FFDIM * HID;

        mfma_gemm<true,  false><<<dim3(HID/64, TOK/64),   dim3(256), 0, stream>>>(hb,   Wq_l,  bq + l*HID,  qb,  HID, HID);
        mfma_gemm<true,  false><<<dim3(HID/64, TOK/64),   dim3(256), 0, stream>>>(hb,   Wk_l,  bk + l*HID,  kb,  HID, HID);
        mfma_gemm<true,  false><<<dim3(HID/64, TOK/64),   dim3(256), 0, stream>>>(hb,   Wv_l,  bv + l*HID,  vb,  HID, HID);
        mfma_gemm<true,  false><<<dim3(HID/64, SPAN2/64), dim3(256), 0, stream>>>(relb, Wpk_l, bpk + l*HID, pkb, HID, HID);
        mfma_gemm<true,  false><<<dim3(HID/64, SPAN2/64), dim3(256), 0, stream>>>(relb, Wpq_l, bpq + l*HID, pqb, HID, HID);

        attn_kernel<<<dim3(SEQ/32, BATCH*NHEAD), dim3(256), 0, stream>>>(qb, kb, vb, pkb, pqb, am, ctx);

        mfma_gemm<false, false><<<dim3(HID/64, TOK/64),   dim3(256), 0, stream>>>(ctx,  Wo_l,  bo + l*HID,  t1,  HID, HID);
        add_ln_kernel<<<dim3(TOK), dim3(256), 0, stream>>>(t1, ln1g + l*HID, ln1b + l*HID, h, hb);

        mfma_gemm<true,  true ><<<dim3(FFDIM/64, TOK/64), dim3(256), 0, stream>>>(hb,   W1_l,  b1 + l*FFDIM, ffb, FFDIM, HID);
        mfma_gemm<false, false><<<dim3(HID/64, TOK/64),   dim3(256), 0, stream>>>(ffb,  W2_l,  b2 + l*HID,  t1,  HID, FFDIM);
        add_ln_kernel<<<dim3(TOK), dim3(256), 0, stream>>>(t1, ln2g + l*HID, ln2b + l*HID, h, hb);
    }

    float* out_f = (float*)d_out;
    copy_f_kernel<<<dim3(TOK*HID/256), dim3(256), 0, stream>>>(h, out_f, TOK*HID);
    cls_kernel<<<dim3(TOK), dim3(32), 0, stream>>>(h, cls_w, cls_b, out_f + TOK*HID);
}